// Round 1
// baseline (525.927 us; speedup 1.0000x reference)
//
#include <hip/hip_runtime.h>

typedef short bf8 __attribute__((ext_vector_type(8)));
typedef float f32x4 __attribute__((ext_vector_type(4)));

__device__ inline unsigned short f2bf(float f) {
    unsigned u = __builtin_bit_cast(unsigned, f);
    u += 0x7FFFu + ((u >> 16) & 1u);
    return (unsigned short)(u >> 16);
}

#define BM 128
#define BN 64
#define BK 32

// C[M,N] = A[M,K] @ W[N,K]^T  (+ bias, + epilogue)
// EPI 0: C = acc + bias
// EPI 1: C = (acc + bias)*scale + shift   (BN inference; q0..q3 = gamma,beta,mean,var)
// EPI 2: attention score: atomicAdd(score[m], sum_n tanh(acc + bias[n] + q0[m/64*N+n]) * q1[n])
template<int EPI>
__global__ __launch_bounds__(256) void gemm_bt(
    const float* __restrict__ A, const float* __restrict__ W,
    const float* __restrict__ bias, float* __restrict__ C,
    int M, int N, int K,
    const float* __restrict__ q0, const float* __restrict__ q1,
    const float* __restrict__ q2, const float* __restrict__ q3,
    float* __restrict__ score)
{
    __shared__ short As[BM][BK + 8];   // row stride 80 B
    __shared__ short Bs[BN][BK + 8];

    const int tid  = threadIdx.x;
    const int lane = tid & 63;
    const int wave = tid >> 6;
    const int wm0  = (wave >> 1) * 64;
    const int wn0  = (wave & 1) * 32;
    const int lr   = lane & 15;
    const int lk   = (lane >> 4) * 8;

    const int m0 = blockIdx.y * BM;
    const int n0 = blockIdx.x * BN;

    const int tr = tid >> 3;   // 0..31
    const int tc = tid & 7;    // 0..7

    f32x4 acc[4][2] = {};

    for (int k0 = 0; k0 < K; k0 += BK) {
        // stage A: 128 x 32 fp32 -> bf16
        #pragma unroll
        for (int rr = 0; rr < BM; rr += 32) {
            int r = rr + tr;
            const float4 v = *reinterpret_cast<const float4*>(
                &A[(size_t)(m0 + r) * K + k0 + tc * 4]);
            unsigned p0 = f2bf(v.x) | ((unsigned)f2bf(v.y) << 16);
            unsigned p1 = f2bf(v.z) | ((unsigned)f2bf(v.w) << 16);
            *reinterpret_cast<uint2*>(&As[r][tc * 4]) = make_uint2(p0, p1);
        }
        // stage W: 64 x 32 fp32 -> bf16 (guard N tail)
        #pragma unroll
        for (int rr = 0; rr < BN; rr += 32) {
            int r = rr + tr;
            int n = n0 + r;
            float4 v = make_float4(0.f, 0.f, 0.f, 0.f);
            if (n < N)
                v = *reinterpret_cast<const float4*>(&W[(size_t)n * K + k0 + tc * 4]);
            unsigned p0 = f2bf(v.x) | ((unsigned)f2bf(v.y) << 16);
            unsigned p1 = f2bf(v.z) | ((unsigned)f2bf(v.w) << 16);
            *reinterpret_cast<uint2*>(&Bs[r][tc * 4]) = make_uint2(p0, p1);
        }
        __syncthreads();
        bf8 av[4], bv[2];
        #pragma unroll
        for (int i = 0; i < 4; ++i)
            av[i] = *reinterpret_cast<const bf8*>(&As[wm0 + i * 16 + lr][lk]);
        #pragma unroll
        for (int j = 0; j < 2; ++j)
            bv[j] = *reinterpret_cast<const bf8*>(&Bs[wn0 + j * 16 + lr][lk]);
        #pragma unroll
        for (int i = 0; i < 4; ++i)
            #pragma unroll
            for (int j = 0; j < 2; ++j)
                acc[i][j] = __builtin_amdgcn_mfma_f32_16x16x32_bf16(
                    av[i], bv[j], acc[i][j], 0, 0, 0);
        __syncthreads();
    }

    if (EPI == 2) {
        // tanh + Vattn projection, reduce over n, atomic into score[m]
        #pragma unroll
        for (int i = 0; i < 4; ++i) {
            #pragma unroll
            for (int r = 0; r < 4; ++r) {
                int m = m0 + wm0 + i * 16 + (lane >> 4) * 4 + r;
                int bidx = m >> 6;   // m / L, L=64
                float s = 0.f;
                #pragma unroll
                for (int j = 0; j < 2; ++j) {
                    int n = n0 + wn0 + j * 16 + lr;
                    s += tanhf(acc[i][j][r] + bias[n] + q0[(size_t)bidx * N + n]) * q1[n];
                }
                #pragma unroll
                for (int off = 1; off < 16; off <<= 1)
                    s += __shfl_xor(s, off);
                if (lr == 0) atomicAdd(&score[m], s);
            }
        }
    } else {
        #pragma unroll
        for (int j = 0; j < 2; ++j) {
            int n = n0 + wn0 + j * 16 + lr;
            if (n >= N) continue;
            float bn_ = bias[n];
            float sc = 1.f, sh = 0.f;
            if (EPI == 1) {
                sc = q0[n] * rsqrtf(q3[n] + 1e-3f);
                sh = q1[n] - q2[n] * sc;
            }
            #pragma unroll
            for (int i = 0; i < 4; ++i) {
                #pragma unroll
                for (int r = 0; r < 4; ++r) {
                    int m = m0 + wm0 + i * 16 + (lane >> 4) * 4 + r;
                    float v = acc[i][j][r] + bn_;
                    if (EPI == 1) v = v * sc + sh;
                    C[(size_t)m * N + n] = v;
                }
            }
        }
    }
}

__global__ void init_score(float* score, const float* vb) {
    int i = blockIdx.x * 256 + threadIdx.x;
    if (i < 8192) score[i] = vb[0];
}

// one block per batch b: softmax over L=64, ctx = attn . features, gin = [ctx, emb[x]]
__global__ __launch_bounds__(256) void softmax_ctx(
    const float* __restrict__ score, const float* __restrict__ features,
    const int* __restrict__ x, const float* __restrict__ emb,
    float* __restrict__ attn_out, float* __restrict__ gin)
{
    int b = blockIdx.x;
    int t = threadIdx.x;
    __shared__ float sa[64];
    if (t < 64) {
        float v = score[b * 64 + t];
        float m = v;
        #pragma unroll
        for (int off = 32; off; off >>= 1) m = fmaxf(m, __shfl_xor(m, off));
        float e = expf(v - m);
        float s = e;
        #pragma unroll
        for (int off = 32; off; off >>= 1) s += __shfl_xor(s, off);
        float a = e / s;
        attn_out[b * 64 + t] = a;
        sa[t] = a;
    }
    __syncthreads();
    for (int e0 = t; e0 < 512; e0 += 256) {
        float c = 0.f;
        #pragma unroll 4
        for (int l = 0; l < 64; ++l)
            c += sa[l] * features[((size_t)b * 64 + l) * 512 + e0];
        gin[(size_t)b * 1024 + e0] = c;
    }
    int xi = x[b];
    for (int e0 = t; e0 < 512; e0 += 256)
        gin[(size_t)b * 1024 + 512 + e0] = emb[(size_t)xi * 512 + e0];
}

__global__ __launch_bounds__(256) void gru_kernel(
    const float* __restrict__ gi, const float* __restrict__ gh,
    const float* __restrict__ h, float* __restrict__ hnew)
{
    int idx = blockIdx.x * 256 + threadIdx.x;   // 131072
    int b = idx >> 10, u = idx & 1023;
    const float* gib = gi + (size_t)b * 3072;
    const float* ghb = gh + (size_t)b * 3072;
    float ir = gib[u], iz = gib[1024 + u], in_ = gib[2048 + u];
    float hr = ghb[u], hz = ghb[1024 + u], hn = ghb[2048 + u];
    float r = 1.f / (1.f + expf(-(ir + hr)));
    float z = 1.f / (1.f + expf(-(iz + hz)));
    float n = tanhf(in_ + r * hn);
    hnew[idx] = (1.f - z) * n + z * h[idx];
}

extern "C" void kernel_launch(void* const* d_in, const int* in_sizes, int n_in,
                              void* d_out, int out_size, void* d_ws, size_t ws_size,
                              hipStream_t stream)
{
    const int*   x        = (const int*)  d_in[0];
    const float* features = (const float*)d_in[1];
    const float* hidden   = (const float*)d_in[2];
    const float* emb      = (const float*)d_in[3];
    const float* Uattn_w  = (const float*)d_in[4];
    const float* Uattn_b  = (const float*)d_in[5];
    const float* Wattn_w  = (const float*)d_in[6];
    const float* Wattn_b  = (const float*)d_in[7];
    const float* Vattn_w  = (const float*)d_in[8];
    const float* Vattn_b  = (const float*)d_in[9];
    const float* W_ih     = (const float*)d_in[10];
    const float* W_hh     = (const float*)d_in[11];
    const float* b_ih     = (const float*)d_in[12];
    const float* b_hh     = (const float*)d_in[13];
    const float* fc_w     = (const float*)d_in[14];
    const float* fc_b     = (const float*)d_in[15];
    const float* bn_gamma = (const float*)d_in[16];
    const float* bn_beta  = (const float*)d_in[17];
    const float* bn_mean  = (const float*)d_in[18];
    const float* bn_var   = (const float*)d_in[19];
    const float* fc2_w    = (const float*)d_in[20];
    const float* fc2_b    = (const float*)d_in[21];

    float* out    = (float*)d_out;
    float* logits = out;                       // 128*50257 = 6432896
    float* hnew   = out + 6432896;             // 131072
    float* attn   = out + 6432896 + 131072;    // 8192

    float* ws     = (float*)d_ws;
    float* Wh     = ws;                 // 131072
    float* scoreb = ws + 131072;        // 8192
    float* gin    = ws + 139264;        // 131072
    float* gi     = ws + 270336;        // 393216
    float* gh     = ws + 663552;        // 393216
    float* y      = ws + 1056768;       // 131072

    init_score<<<32, 256, 0, stream>>>(scoreb, Vattn_b);

    // Wh = h @ Wattn_w^T + Wattn_b
    gemm_bt<0><<<dim3(16, 1), 256, 0, stream>>>(hidden, Wattn_w, Wattn_b, Wh,
        128, 1024, 1024, nullptr, nullptr, nullptr, nullptr, nullptr);

    // score[b,l] += sum_u tanh(Uf + Uattn_b + Wh) * Vattn_w
    gemm_bt<2><<<dim3(16, 64), 256, 0, stream>>>(features, Uattn_w, Uattn_b, nullptr,
        8192, 1024, 512, Wh, Vattn_w, nullptr, nullptr, scoreb);

    softmax_ctx<<<128, 256, 0, stream>>>(scoreb, features, x, emb, attn, gin);

    // gi = gin @ W_ih^T + b_ih ; gh = h @ W_hh^T + b_hh
    gemm_bt<0><<<dim3(48, 1), 256, 0, stream>>>(gin, W_ih, b_ih, gi,
        128, 3072, 1024, nullptr, nullptr, nullptr, nullptr, nullptr);
    gemm_bt<0><<<dim3(48, 1), 256, 0, stream>>>(hidden, W_hh, b_hh, gh,
        128, 3072, 1024, nullptr, nullptr, nullptr, nullptr, nullptr);

    gru_kernel<<<512, 256, 0, stream>>>(gi, gh, hidden, hnew);

    // y = BN(h_new @ fc_w^T + fc_b)
    gemm_bt<1><<<dim3(16, 1), 256, 0, stream>>>(hnew, fc_w, fc_b, y,
        128, 1024, 1024, bn_gamma, bn_beta, bn_mean, bn_var, nullptr);

    // logits = y @ fc2_w^T + fc2_b
    gemm_bt<0><<<dim3(786, 1), 256, 0, stream>>>(y, fc2_w, fc2_b, logits,
        128, 50257, 1024, nullptr, nullptr, nullptr, nullptr, nullptr);
}

// Round 3
// 208.700 us; speedup vs baseline: 2.5200x; 2.5200x over previous
//
#include <hip/hip_runtime.h>

typedef short bf8 __attribute__((ext_vector_type(8)));
typedef float f32x4 __attribute__((ext_vector_type(4)));

__device__ inline short f2bfs(float f) {
    unsigned u = __builtin_bit_cast(unsigned, f);
    u += 0x7FFFu + ((u >> 16) & 1u);
    return (short)(u >> 16);
}

__device__ inline unsigned pk2(float x, float y) {
    return (unsigned)(unsigned short)f2bfs(x) |
           ((unsigned)(unsigned short)f2bfs(y) << 16);
}

__device__ inline bf8 cvt_frag(f32x4 lo, f32x4 hi) {
    union { bf8 v; unsigned u[4]; } r;
    r.u[0] = pk2(lo[0], lo[1]);
    r.u[1] = pk2(lo[2], lo[3]);
    r.u[2] = pk2(hi[0], hi[1]);
    r.u[3] = pk2(hi[2], hi[3]);
    return r.v;
}

__device__ inline void gl_lds16(const void* g, void* l) {
    __builtin_amdgcn_global_load_lds(
        (const __attribute__((address_space(1))) unsigned int*)g,
        (__attribute__((address_space(3))) unsigned int*)l,
        16, 0, 0);
}

// C[M,N] = A[M,K] @ W[N,K]^T (+bias, +epilogue). BN=64, BK=64, 4 waves (2x2).
// ABF: A is bf16 (pitch lda), else fp32. OBF: C stored as bf16.
// EPI 0: C = acc + bias
// EPI 1: C = BN-inference epilogue (q0..q3 = gamma,beta,mean,var)
// EPI 2: atomicAdd(score[m], sum_n tanh(acc + bias[n] + q0[(m>>6)*N+n]) * q1[n])
template<int EPI, int BM_, bool ABF, bool OBF>
__global__ __launch_bounds__(256) void gemm_bt(
    const void* __restrict__ Av, const float* __restrict__ W,
    const float* __restrict__ bias, void* __restrict__ Cv,
    int M, int N, int K, int lda,
    const float* __restrict__ q0, const float* __restrict__ q1,
    const float* __restrict__ q2, const float* __restrict__ q3,
    float* __restrict__ score)
{
    constexpr int FM  = BM_ / 32;              // m-frags per wave
    constexpr int ASZ = ABF ? BM_ * 128 : BM_ * 256;
    __shared__ __align__(1024) char smem[ASZ + 16384];
    char* sA = smem;
    char* sW = smem + ASZ;

    const int tid  = threadIdx.x;
    const int lane = tid & 63;
    const int wave = tid >> 6;
    const int wm0  = (wave >> 1) * (BM_ / 2);
    const int wn0  = (wave & 1) * 32;
    const int m0   = blockIdx.y * BM_;
    const int n0   = blockIdx.x * 64;

    f32x4 acc[FM][2] = {};

    for (int k0 = 0; k0 < K; k0 += 64) {
        // ---- stage A ----
        if constexpr (ABF) {
            const short* A = (const short*)Av;
            constexpr int APW = BM_ / 32;      // 1KB chunks per wave
            #pragma unroll
            for (int cc = 0; cc < APW; ++cc) {
                int c  = wave * APW + cc;
                int r  = c * 8 + (lane >> 3);
                int sl = (lane & 7) ^ (r & 7);   // inverse-swizzled source slot
                gl_lds16(&A[(size_t)(m0 + r) * lda + k0 + sl * 8], sA + c * 1024);
            }
        } else {
            const float* A = (const float*)Av;
            constexpr int APW = BM_ / 16;
            #pragma unroll
            for (int cc = 0; cc < APW; ++cc) {
                int c  = wave * APW + cc;
                int r  = c * 4 + (lane >> 4);
                int sl = (lane & 15) ^ (((r & 7) << 1) | ((r >> 3) & 1));
                gl_lds16(&A[(size_t)(m0 + r) * lda + k0 + sl * 4], sA + c * 1024);
            }
        }
        // ---- stage W (fp32) ----
        #pragma unroll
        for (int cc = 0; cc < 4; ++cc) {
            int c  = wave * 4 + cc;
            int r  = c * 4 + (lane >> 4);
            int sl = (lane & 15) ^ (((r & 7) << 1) | ((r >> 3) & 1));
            int rg = n0 + r; rg = rg < N ? rg : N - 1;   // clamp tail (result discarded)
            gl_lds16(&W[(size_t)rg * K + k0 + sl * 4], sW + c * 1024);
        }
        __syncthreads();

        #pragma unroll
        for (int ks = 0; ks < 2; ++ks) {
            bf8 av[FM], bv[2];
            #pragma unroll
            for (int i = 0; i < FM; ++i) {
                int ra = wm0 + i * 16 + (lane & 15);
                if constexpr (ABF) {
                    int bc = ks * 64 + ((lane >> 4) * 16);
                    av[i] = *reinterpret_cast<const bf8*>(
                        sA + ra * 128 + (bc ^ ((ra & 7) << 4)));
                } else {
                    int bl = ks * 128 + ((lane >> 4) * 32);
                    int sw = ((ra & 7) << 5) | ((ra & 8) << 1);
                    f32x4 lo = *reinterpret_cast<const f32x4*>(sA + ra * 256 + (bl ^ sw));
                    f32x4 hi = *reinterpret_cast<const f32x4*>(sA + ra * 256 + ((bl + 16) ^ sw));
                    av[i] = cvt_frag(lo, hi);
                }
            }
            #pragma unroll
            for (int j = 0; j < 2; ++j) {
                int rb = wn0 + j * 16 + (lane & 15);
                int bl = ks * 128 + ((lane >> 4) * 32);
                int sw = ((rb & 7) << 5) | ((rb & 8) << 1);
                f32x4 lo = *reinterpret_cast<const f32x4*>(sW + rb * 256 + (bl ^ sw));
                f32x4 hi = *reinterpret_cast<const f32x4*>(sW + rb * 256 + ((bl + 16) ^ sw));
                bv[j] = cvt_frag(lo, hi);
            }
            #pragma unroll
            for (int i = 0; i < FM; ++i)
                #pragma unroll
                for (int j = 0; j < 2; ++j)
                    acc[i][j] = __builtin_amdgcn_mfma_f32_16x16x32_bf16(
                        av[i], bv[j], acc[i][j], 0, 0, 0);
        }
        __syncthreads();
    }

    if constexpr (EPI == 2) {
        #pragma unroll
        for (int i = 0; i < FM; ++i) {
            #pragma unroll
            for (int r = 0; r < 4; ++r) {
                int m = m0 + wm0 + i * 16 + (lane >> 4) * 4 + r;
                int bidx = m >> 6;
                float s = 0.f;
                #pragma unroll
                for (int j = 0; j < 2; ++j) {
                    int n = n0 + wn0 + j * 16 + (lane & 15);
                    s += tanhf(acc[i][j][r] + bias[n] + q0[(size_t)bidx * N + n]) * q1[n];
                }
                #pragma unroll
                for (int off = 1; off < 16; off <<= 1)
                    s += __shfl_xor(s, off);
                if ((lane & 15) == 0) atomicAdd(&score[m], s);
            }
        }
    } else {
        #pragma unroll
        for (int j = 0; j < 2; ++j) {
            int n = n0 + wn0 + j * 16 + (lane & 15);
            if (n >= N) continue;
            float bn_ = bias[n];
            float sc = 1.f, sh = 0.f;
            if constexpr (EPI == 1) {
                sc = q0[n] * rsqrtf(q3[n] + 1e-3f);
                sh = q1[n] - q2[n] * sc;
            }
            #pragma unroll
            for (int i = 0; i < FM; ++i) {
                #pragma unroll
                for (int r = 0; r < 4; ++r) {
                    int m = m0 + wm0 + i * 16 + (lane >> 4) * 4 + r;
                    float v = acc[i][j][r] + bn_;
                    if constexpr (EPI == 1) v = v * sc + sh;
                    if constexpr (OBF) ((short*)Cv)[(size_t)m * N + n] = f2bfs(v);
                    else               ((float*)Cv)[(size_t)m * N + n] = v;
                }
            }
        }
    }
}

// hidden -> bf16 copy; init score to Vattn_b. 64 blocks x 256.
__global__ __launch_bounds__(256) void prep(
    const float* __restrict__ h, short* __restrict__ h_bf,
    float* __restrict__ score, const float* __restrict__ vb)
{
    int t = blockIdx.x * 256 + threadIdx.x;    // 16384
    float4 v0 = *reinterpret_cast<const float4*>(h + (size_t)t * 8);
    float4 v1 = *reinterpret_cast<const float4*>(h + (size_t)t * 8 + 4);
    union { unsigned u[4]; uint4 q; } r;
    r.u[0] = pk2(v0.x, v0.y);
    r.u[1] = pk2(v0.z, v0.w);
    r.u[2] = pk2(v1.x, v1.y);
    r.u[3] = pk2(v1.z, v1.w);
    *reinterpret_cast<uint4*>(h_bf + (size_t)t * 8) = r.q;
    if (t < 1024) {
        float v = vb[0];
        float4 vv = make_float4(v, v, v, v);
        *reinterpret_cast<float4*>(score + t * 8)     = vv;
        *reinterpret_cast<float4*>(score + t * 8 + 4) = vv;
    }
}

// one block per batch b: softmax over L=64, ctx = attn . features, gin_bf = [ctx, emb[x]] (bf16)
__global__ __launch_bounds__(256) void softmax_ctx(
    const float* __restrict__ score, const float* __restrict__ features,
    const int* __restrict__ x, const float* __restrict__ emb,
    float* __restrict__ attn_out, short* __restrict__ gin_bf)
{
    int b = blockIdx.x;
    int t = threadIdx.x;
    __shared__ float sa[64];
    if (t < 64) {
        float v = score[b * 64 + t];
        float m = v;
        #pragma unroll
        for (int off = 32; off; off >>= 1) m = fmaxf(m, __shfl_xor(m, off));
        float e = expf(v - m);
        float s = e;
        #pragma unroll
        for (int off = 32; off; off >>= 1) s += __shfl_xor(s, off);
        float a = e / s;
        attn_out[b * 64 + t] = a;
        sa[t] = a;
    }
    __syncthreads();
    for (int e0 = t; e0 < 512; e0 += 256) {
        float c = 0.f;
        #pragma unroll 4
        for (int l = 0; l < 64; ++l)
            c += sa[l] * features[((size_t)b * 64 + l) * 512 + e0];
        gin_bf[(size_t)b * 1024 + e0] = f2bfs(c);
    }
    int xi = x[b];
    for (int e0 = t; e0 < 512; e0 += 256)
        gin_bf[(size_t)b * 1024 + 512 + e0] = f2bfs(emb[(size_t)xi * 512 + e0]);
}

__global__ __launch_bounds__(256) void gru_kernel(
    const float* __restrict__ gi, const float* __restrict__ gh,
    const float* __restrict__ h, float* __restrict__ hnew,
    short* __restrict__ hnew_bf)
{
    int idx = blockIdx.x * 256 + threadIdx.x;   // 131072
    int b = idx >> 10, u = idx & 1023;
    const float* gib = gi + (size_t)b * 3072;
    const float* ghb = gh + (size_t)b * 3072;
    float ir = gib[u], iz = gib[1024 + u], in_ = gib[2048 + u];
    float hr = ghb[u], hz = ghb[1024 + u], hn = ghb[2048 + u];
    float r = 1.f / (1.f + expf(-(ir + hr)));
    float z = 1.f / (1.f + expf(-(iz + hz)));
    float n = tanhf(in_ + r * hn);
    float val = (1.f - z) * n + z * h[idx];
    hnew[idx] = val;
    hnew_bf[idx] = f2bfs(val);
}

extern "C" void kernel_launch(void* const* d_in, const int* in_sizes, int n_in,
                              void* d_out, int out_size, void* d_ws, size_t ws_size,
                              hipStream_t stream)
{
    const int*   x        = (const int*)  d_in[0];
    const float* features = (const float*)d_in[1];
    const float* hidden   = (const float*)d_in[2];
    const float* emb      = (const float*)d_in[3];
    const float* Uattn_w  = (const float*)d_in[4];
    const float* Uattn_b  = (const float*)d_in[5];
    const float* Wattn_w  = (const float*)d_in[6];
    const float* Wattn_b  = (const float*)d_in[7];
    const float* Vattn_w  = (const float*)d_in[8];
    const float* Vattn_b  = (const float*)d_in[9];
    const float* W_ih     = (const float*)d_in[10];
    const float* W_hh     = (const float*)d_in[11];
    const float* b_ih     = (const float*)d_in[12];
    const float* b_hh     = (const float*)d_in[13];
    const float* fc_w     = (const float*)d_in[14];
    const float* fc_b     = (const float*)d_in[15];
    const float* bn_gamma = (const float*)d_in[16];
    const float* bn_beta  = (const float*)d_in[17];
    const float* bn_mean  = (const float*)d_in[18];
    const float* bn_var   = (const float*)d_in[19];
    const float* fc2_w    = (const float*)d_in[20];
    const float* fc2_b    = (const float*)d_in[21];

    float* out    = (float*)d_out;
    float* logits = out;                       // 128*50257
    float* hnew   = out + 6432896;             // 131072
    float* attn   = out + 6432896 + 131072;    // 8192

    float* ws        = (float*)d_ws;
    float* Wh        = ws;                     // 131072 f
    float* scoreb    = ws + 131072;            // 8192 f
    float* gi        = ws + 139264;            // 393216 f
    float* gh        = ws + 532480;            // 393216 f
    short* hidden_bf = (short*)(ws + 925696);  // 131072 bf16
    short* gin_bf    = (short*)(ws + 991232);  // 131072 bf16
    short* hnew_bf   = (short*)(ws + 1056768); // 131072 bf16
    short* y_bf      = (short*)(ws + 1122304); // 131072 bf16

    prep<<<64, 256, 0, stream>>>(hidden, hidden_bf, scoreb, Vattn_b);

    // Wh = h @ Wattn_w^T + Wattn_b
    gemm_bt<0, 64, true, false><<<dim3(16, 2), 256, 0, stream>>>(
        hidden_bf, Wattn_w, Wattn_b, Wh, 128, 1024, 1024, 1024,
        nullptr, nullptr, nullptr, nullptr, nullptr);

    // score[b,l] += sum_u tanh(Uf + Uattn_b + Wh) * Vattn_w
    gemm_bt<2, 128, false, false><<<dim3(16, 64), 256, 0, stream>>>(
        features, Uattn_w, Uattn_b, nullptr, 8192, 1024, 512, 512,
        Wh, Vattn_w, nullptr, nullptr, scoreb);

    softmax_ctx<<<128, 256, 0, stream>>>(scoreb, features, x, emb, attn, gin_bf);

    // gi = gin @ W_ih^T + b_ih ; gh = h @ W_hh^T + b_hh
    gemm_bt<0, 64, true, false><<<dim3(48, 2), 256, 0, stream>>>(
        gin_bf, W_ih, b_ih, gi, 128, 3072, 1024, 1024,
        nullptr, nullptr, nullptr, nullptr, nullptr);
    gemm_bt<0, 64, true, false><<<dim3(48, 2), 256, 0, stream>>>(
        hidden_bf, W_hh, b_hh, gh, 128, 3072, 1024, 1024,
        nullptr, nullptr, nullptr, nullptr, nullptr);

    gru_kernel<<<512, 256, 0, stream>>>(gi, gh, hidden, hnew, hnew_bf);

    // y = BN(h_new @ fc_w^T + fc_b) -> bf16
    gemm_bt<1, 64, true, true><<<dim3(16, 2), 256, 0, stream>>>(
        hnew_bf, fc_w, fc_b, y_bf, 128, 1024, 1024, 1024,
        bn_gamma, bn_beta, bn_mean, bn_var, nullptr);

    // logits = y @ fc2_w^T + fc2_b
    gemm_bt<0, 128, true, false><<<dim3(786, 1), 256, 0, stream>>>(
        y_bf, fc2_w, fc2_b, logits, 128, 50257, 1024, 1024,
        nullptr, nullptr, nullptr, nullptr, nullptr);
}

// Round 5
// 175.436 us; speedup vs baseline: 2.9978x; 1.1896x over previous
//
#include <hip/hip_runtime.h>

typedef short bf8 __attribute__((ext_vector_type(8)));
typedef float f32x4 __attribute__((ext_vector_type(4)));

__device__ inline short f2bfs(float f) {
    unsigned u = __builtin_bit_cast(unsigned, f);
    u += 0x7FFFu + ((u >> 16) & 1u);
    return (short)(u >> 16);
}

__device__ inline unsigned pk2(float x, float y) {
    return (unsigned)(unsigned short)f2bfs(x) |
           ((unsigned)(unsigned short)f2bfs(y) << 16);
}

__device__ inline bf8 cvt_frag(f32x4 lo, f32x4 hi) {
    union { bf8 v; unsigned u[4]; } r;
    r.u[0] = pk2(lo[0], lo[1]);
    r.u[1] = pk2(lo[2], lo[3]);
    r.u[2] = pk2(hi[0], hi[1]);
    r.u[3] = pk2(hi[2], hi[3]);
    return r.v;
}

__device__ inline void gl_lds16(const void* g, void* l) {
    __builtin_amdgcn_global_load_lds(
        (const __attribute__((address_space(1))) unsigned int*)g,
        (__attribute__((address_space(3))) unsigned int*)l,
        16, 0, 0);
}

// C[M,N] = A[M,K] @ W[N,K]^T (+bias, +epilogue).
// A bf16 (pitch lda), W fp32 (cvt on LDS read). BN=64, BK=64, 4 waves (2x2).
// 2-phase double-buffered: stage(t+1) issued BEFORE compute(t); single
// barrier per tile so the compiler's vmcnt(0) drain lands after compute.
// EPI 0: C = acc + bias
// EPI 1: BN-inference epilogue (q0..q3 = gamma,beta,mean,var)
// EPI 2: atomicAdd(score[m], sum_n tanh(acc + bias[n] + q0[(m>>6)*N+n]) * q1[n])
template<int EPI, int BM_, bool OBF>
__global__ __launch_bounds__(256) void gemm_bt(
    const short* __restrict__ A, const float* __restrict__ W,
    const float* __restrict__ bias, void* __restrict__ Cv,
    int M, int N, int K, int lda,
    const float* __restrict__ q0, const float* __restrict__ q1,
    const float* __restrict__ q2, const float* __restrict__ q3,
    float* __restrict__ score)
{
    constexpr int FM  = BM_ / 32;          // m-frags per wave
    constexpr int ASZ = BM_ * 128;         // bf16 A tile bytes (BM_ x 64)
    __shared__ __align__(1024) char smem[2 * ASZ + 32768];

    const int tid  = threadIdx.x;
    const int lane = tid & 63;
    const int wave = tid >> 6;
    const int wm0  = (wave >> 1) * (BM_ / 2);
    const int wn0  = (wave & 1) * 32;
    const int m0   = blockIdx.y * BM_;
    const int n0   = blockIdx.x * 64;

    f32x4 acc[FM][2] = {};

    auto stage = [&](int buf, int k0) {
        constexpr int APW = BM_ / 32;      // 1KB chunks per wave (A)
        char* sA = smem + buf * ASZ;
        char* sW = smem + 2 * ASZ + buf * 16384;
        #pragma unroll
        for (int cc = 0; cc < APW; ++cc) {
            int c  = wave * APW + cc;
            int r  = c * 8 + (lane >> 3);
            int sl = (lane & 7) ^ (r & 7);
            gl_lds16(&A[(size_t)(m0 + r) * lda + k0 + sl * 8], sA + c * 1024);
        }
        #pragma unroll
        for (int cc = 0; cc < 4; ++cc) {
            int c  = wave * 4 + cc;
            int r  = c * 4 + (lane >> 4);
            int sl = (lane & 15) ^ (((r & 7) << 1) | ((r >> 3) & 1));
            int rg = n0 + r; rg = rg < N ? rg : N - 1;   // clamp tail
            gl_lds16(&W[(size_t)rg * K + k0 + sl * 4], sW + c * 1024);
        }
    };

    auto compute = [&](int buf) {
        char* sA = smem + buf * ASZ;
        char* sW = smem + 2 * ASZ + buf * 16384;
        #pragma unroll
        for (int ks = 0; ks < 2; ++ks) {
            bf8 av[FM], bv[2];
            #pragma unroll
            for (int i = 0; i < FM; ++i) {
                int ra = wm0 + i * 16 + (lane & 15);
                int bc = ks * 64 + ((lane >> 4) * 16);
                av[i] = *reinterpret_cast<const bf8*>(
                    sA + ra * 128 + (bc ^ ((ra & 7) << 4)));
            }
            #pragma unroll
            for (int j = 0; j < 2; ++j) {
                int rb = wn0 + j * 16 + (lane & 15);
                int bl = ks * 128 + ((lane >> 4) * 32);
                int sw = ((rb & 7) << 5) | ((rb & 8) << 1);
                f32x4 lo = *reinterpret_cast<const f32x4*>(sW + rb * 256 + (bl ^ sw));
                f32x4 hi = *reinterpret_cast<const f32x4*>(sW + rb * 256 + ((bl + 16) ^ sw));
                bv[j] = cvt_frag(lo, hi);
            }
            #pragma unroll
            for (int i = 0; i < FM; ++i)
                #pragma unroll
                for (int j = 0; j < 2; ++j)
                    acc[i][j] = __builtin_amdgcn_mfma_f32_16x16x32_bf16(
                        av[i], bv[j], acc[i][j], 0, 0, 0);
        }
    };

    const int nt = K >> 6;
    int cur = 0;
    stage(0, 0);
    __syncthreads();                        // drain tile0 loads
    for (int t = 0; t < nt - 1; ++t) {
        stage(cur ^ 1, (t + 1) << 6);       // issue next tile early
        compute(cur);                       // overlap latency with MFMA
        __syncthreads();                    // vmcnt(0)+lgkm drain after compute
        cur ^= 1;
    }
    compute(cur);

    if constexpr (EPI == 2) {
        #pragma unroll
        for (int i = 0; i < FM; ++i) {
            #pragma unroll
            for (int r = 0; r < 4; ++r) {
                int m = m0 + wm0 + i * 16 + (lane >> 4) * 4 + r;
                int bidx = m >> 6;
                float s = 0.f;
                #pragma unroll
                for (int j = 0; j < 2; ++j) {
                    int n = n0 + wn0 + j * 16 + (lane & 15);
                    s += tanhf(acc[i][j][r] + bias[n] + q0[(size_t)bidx * N + n]) * q1[n];
                }
                #pragma unroll
                for (int off = 1; off < 16; off <<= 1)
                    s += __shfl_xor(s, off);
                if ((lane & 15) == 0) atomicAdd(&score[m], s);
            }
        }
    } else {
        #pragma unroll
        for (int j = 0; j < 2; ++j) {
            int n = n0 + wn0 + j * 16 + (lane & 15);
            if (n >= N) continue;
            float bn_ = bias[n];
            float sc = 1.f, sh = 0.f;
            if constexpr (EPI == 1) {
                sc = q0[n] * rsqrtf(q3[n] + 1e-3f);
                sh = q1[n] - q2[n] * sc;
            }
            #pragma unroll
            for (int i = 0; i < FM; ++i) {
                #pragma unroll
                for (int r = 0; r < 4; ++r) {
                    int m = m0 + wm0 + i * 16 + (lane >> 4) * 4 + r;
                    float v = acc[i][j][r] + bn_;
                    if constexpr (EPI == 1) v = v * sc + sh;
                    if constexpr (OBF) ((short*)Cv)[(size_t)m * N + n] = f2bfs(v);
                    else               ((float*)Cv)[(size_t)m * N + n] = v;
                }
            }
        }
    }
}

// grid-stride fp32 -> bf16 (8 elems/thread)
__global__ __launch_bounds__(256) void cvt_bf16(
    const float* __restrict__ src, short* __restrict__ dst, int n8)
{
    for (int t = blockIdx.x * 256 + threadIdx.x; t < n8; t += gridDim.x * 256) {
        float4 v0 = *reinterpret_cast<const float4*>(src + (size_t)t * 8);
        float4 v1 = *reinterpret_cast<const float4*>(src + (size_t)t * 8 + 4);
        union { unsigned u[4]; uint4 q; } r;
        r.u[0] = pk2(v0.x, v0.y);
        r.u[1] = pk2(v0.z, v0.w);
        r.u[2] = pk2(v1.x, v1.y);
        r.u[3] = pk2(v1.z, v1.w);
        *reinterpret_cast<uint4*>(dst + (size_t)t * 8) = r.q;
    }
}

// hidden -> bf16; init score to Vattn_b. 64 blocks x 256.
__global__ __launch_bounds__(256) void prep(
    const float* __restrict__ h, short* __restrict__ h_bf,
    float* __restrict__ score, const float* __restrict__ vb)
{
    int t = blockIdx.x * 256 + threadIdx.x;    // 16384
    float4 v0 = *reinterpret_cast<const float4*>(h + (size_t)t * 8);
    float4 v1 = *reinterpret_cast<const float4*>(h + (size_t)t * 8 + 4);
    union { unsigned u[4]; uint4 q; } r;
    r.u[0] = pk2(v0.x, v0.y);
    r.u[1] = pk2(v0.z, v0.w);
    r.u[2] = pk2(v1.x, v1.y);
    r.u[3] = pk2(v1.z, v1.w);
    *reinterpret_cast<uint4*>(h_bf + (size_t)t * 8) = r.q;
    if (t < 1024) {
        float v = vb[0];
        float4 vv = make_float4(v, v, v, v);
        *reinterpret_cast<float4*>(score + t * 8)     = vv;
        *reinterpret_cast<float4*>(score + t * 8 + 4) = vv;
    }
}

// one block per batch b: softmax over L=64, ctx = attn . features, gin_bf = [ctx, emb[x]]
__global__ __launch_bounds__(256) void softmax_ctx(
    const float* __restrict__ score, const float* __restrict__ features,
    const int* __restrict__ x, const float* __restrict__ emb,
    float* __restrict__ attn_out, short* __restrict__ gin_bf)
{
    int b = blockIdx.x;
    int t = threadIdx.x;
    __shared__ float sa[64];
    if (t < 64) {
        float v = score[b * 64 + t];
        float m = v;
        #pragma unroll
        for (int off = 32; off; off >>= 1) m = fmaxf(m, __shfl_xor(m, off));
        float e = expf(v - m);
        float s = e;
        #pragma unroll
        for (int off = 32; off; off >>= 1) s += __shfl_xor(s, off);
        float a = e / s;
        attn_out[b * 64 + t] = a;
        sa[t] = a;
    }
    __syncthreads();
    for (int e0 = t; e0 < 512; e0 += 256) {
        float c = 0.f;
        #pragma unroll 4
        for (int l = 0; l < 64; ++l)
            c += sa[l] * features[((size_t)b * 64 + l) * 512 + e0];
        gin_bf[(size_t)b * 1024 + e0] = f2bfs(c);
    }
    int xi = x[b];
    for (int e0 = t; e0 < 512; e0 += 256)
        gin_bf[(size_t)b * 1024 + 512 + e0] = f2bfs(emb[(size_t)xi * 512 + e0]);
}

__global__ __launch_bounds__(256) void gru_kernel(
    const float* __restrict__ gi, const float* __restrict__ gh,
    const float* __restrict__ h, float* __restrict__ hnew,
    short* __restrict__ hnew_bf)
{
    int idx = blockIdx.x * 256 + threadIdx.x;   // 131072
    int b = idx >> 10, u = idx & 1023;
    const float* gib = gi + (size_t)b * 3072;
    const float* ghb = gh + (size_t)b * 3072;
    float ir = gib[u], iz = gib[1024 + u], in_ = gib[2048 + u];
    float hr = ghb[u], hz = ghb[1024 + u], hn = ghb[2048 + u];
    float r = 1.f / (1.f + expf(-(ir + hr)));
    float z = 1.f / (1.f + expf(-(iz + hz)));
    float n = tanhf(in_ + r * hn);
    float val = (1.f - z) * n + z * h[idx];
    hnew[idx] = val;
    hnew_bf[idx] = f2bfs(val);
}

extern "C" void kernel_launch(void* const* d_in, const int* in_sizes, int n_in,
                              void* d_out, int out_size, void* d_ws, size_t ws_size,
                              hipStream_t stream)
{
    const int*   x        = (const int*)  d_in[0];
    const float* features = (const float*)d_in[1];
    const float* hidden   = (const float*)d_in[2];
    const float* emb      = (const float*)d_in[3];
    const float* Uattn_w  = (const float*)d_in[4];
    const float* Uattn_b  = (const float*)d_in[5];
    const float* Wattn_w  = (const float*)d_in[6];
    const float* Wattn_b  = (const float*)d_in[7];
    const float* Vattn_w  = (const float*)d_in[8];
    const float* Vattn_b  = (const float*)d_in[9];
    const float* W_ih     = (const float*)d_in[10];
    const float* W_hh     = (const float*)d_in[11];
    const float* b_ih     = (const float*)d_in[12];
    const float* b_hh     = (const float*)d_in[13];
    const float* fc_w     = (const float*)d_in[14];
    const float* fc_b     = (const float*)d_in[15];
    const float* bn_gamma = (const float*)d_in[16];
    const float* bn_beta  = (const float*)d_in[17];
    const float* bn_mean  = (const float*)d_in[18];
    const float* bn_var   = (const float*)d_in[19];
    const float* fc2_w    = (const float*)d_in[20];
    const float* fc2_b    = (const float*)d_in[21];

    float* out    = (float*)d_out;
    float* logits = out;                       // 128*50257
    float* hnew   = out + 6432896;             // 131072
    float* attn   = out + 6432896 + 131072;    // 8192

    float* ws        = (float*)d_ws;
    float* Wh        = ws;                      // 131072 f
    float* scoreb    = ws + 131072;             // 8192 f
    float* gi        = ws + 139264;             // 393216 f
    float* gh        = ws + 532480;             // 393216 f
    short* hidden_bf = (short*)(ws + 925696);   // 131072 bf16
    short* gin_bf    = (short*)(ws + 991232);   // 131072 bf16
    short* hnew_bf   = (short*)(ws + 1056768);  // 131072 bf16
    short* y_bf      = (short*)(ws + 1122304);  // 131072 bf16
    short* feat_bf   = (short*)(ws + 1187840);  // 4194304 bf16

    prep<<<64, 256, 0, stream>>>(hidden, hidden_bf, scoreb, Vattn_b);
    cvt_bf16<<<2048, 256, 0, stream>>>(features, feat_bf, 4194304 / 8);

    // Wh = h @ Wattn_w^T + Wattn_b
    gemm_bt<0, 64, false><<<dim3(16, 2), 256, 0, stream>>>(
        hidden_bf, Wattn_w, Wattn_b, Wh, 128, 1024, 1024, 1024,
        nullptr, nullptr, nullptr, nullptr, nullptr);

    // score[b,l] += sum_u tanh(Uf + Uattn_b + Wh) * Vattn_w
    gemm_bt<2, 128, false><<<dim3(16, 64), 256, 0, stream>>>(
        feat_bf, Uattn_w, Uattn_b, nullptr, 8192, 1024, 512, 512,
        Wh, Vattn_w, nullptr, nullptr, scoreb);

    softmax_ctx<<<128, 256, 0, stream>>>(scoreb, features, x, emb, attn, gin_bf);

    // gi = gin @ W_ih^T + b_ih ; gh = h @ W_hh^T + b_hh
    gemm_bt<0, 64, false><<<dim3(48, 2), 256, 0, stream>>>(
        gin_bf, W_ih, b_ih, gi, 128, 3072, 1024, 1024,
        nullptr, nullptr, nullptr, nullptr, nullptr);
    gemm_bt<0, 64, false><<<dim3(48, 2), 256, 0, stream>>>(
        hidden_bf, W_hh, b_hh, gh, 128, 3072, 1024, 1024,
        nullptr, nullptr, nullptr, nullptr, nullptr);

    gru_kernel<<<512, 256, 0, stream>>>(gi, gh, hidden, hnew, hnew_bf);

    // y = BN(h_new @ fc_w^T + fc_b) -> bf16
    gemm_bt<1, 64, true><<<dim3(16, 2), 256, 0, stream>>>(
        hnew_bf, fc_w, fc_b, y_bf, 128, 1024, 1024, 1024,
        bn_gamma, bn_beta, bn_mean, bn_var, nullptr);

    // logits = y @ fc2_w^T + fc2_b
    gemm_bt<0, 128, false><<<dim3(786, 1), 256, 0, stream>>>(
        y_bf, fc2_w, fc2_b, logits, 128, 50257, 1024, 1024,
        nullptr, nullptr, nullptr, nullptr, nullptr);
}